// Round 4
// baseline (2483.833 us; speedup 1.0000x reference)
//
#include <hip/hip_runtime.h>

// Sinkhorn distance, 8 batches x 2048 points x 2 dims, 50 iters, eps=0.1.
// v5 = v4 algorithm with hang-proof deadman (worst case ~300ms, fails
// verification visibly instead of tripping the watchdog):
//  - arrival = single-writer RELEASE store to own flag slot (no atomicAdd,
//    no RMW serialization at the coherence point — v3's 15.5us/crossing)
//  - detection = each block's wave0 polls all 64 flags with ONE per-lane
//    relaxed load + __all, then acquire-fences.
//  - j-side rank-2 factors ping-pong through two 64-VGPR buffers; next
//    phase's factors re-loaded (L2-hit, constant data) BETWEEN the flag
//    store and the poll loop, hiding load latency under the barrier wait.

#define P 2048
#define NB 8
constexpr float SCALE = 14.426950408889634f; // log2(e) / eps, eps = 0.1
constexpr float INV4S = 1.0f / (4.0f * SCALE);

typedef float vf4 __attribute__((ext_vector_type(4)));

// ws layout (floats):
// 0       jpY   float2[8*2048]   (32768 f)
// 32768   jpX   float2[8*2048]   (32768 f)
// 65536   rowX  float4[8*2048]   (65536 f)
// 131072  rowY  float4[8*2048]   (65536 f)
// 196608  u[16384]
// 212992  v[16384]
// 229376  partial[512]
// 229888  flags: unsigned[512]  — flags[b*64 + i], 256B per batch

__global__ void setup_kernel(const float* __restrict__ x, const float* __restrict__ yy,
                             float2* __restrict__ jpY, float2* __restrict__ jpX,
                             float4* __restrict__ rowX, float4* __restrict__ rowY,
                             float* __restrict__ u, float* __restrict__ v,
                             float* __restrict__ partial, unsigned* __restrict__ flags) {
    const int n = blockIdx.x;
    const int t = threadIdx.x;
    __shared__ float redx[256], redy[256];
    float xm0[8], xm1[8], ym0[8], ym1[8];
    float sx = 0.f, sy = 0.f;
    #pragma unroll
    for (int k = 0; k < 8; ++k) {
        int p = t + 256 * k;
        size_t base = ((size_t)n * P + p) * 2;
        float a0 = x[base + 0];
        float a1 = x[base + 1];
        float b0 = yy[base + 0];
        float b1 = yy[base + 1];
        // mask = (x != -1); applied to BOTH x and y (per reference)
        float m0 = (a0 != -1.0f) ? 1.0f : 0.0f;
        float m1 = (a1 != -1.0f) ? 1.0f : 0.0f;
        a0 *= m0; a1 *= m1; b0 *= m0; b1 *= m1;
        xm0[k] = a0; xm1[k] = a1; ym0[k] = b0; ym1[k] = b1;
        sx = fmaf(a1, a1, sx);
        sy = fmaf(b1, b1, sy);
    }
    redx[t] = sx; redy[t] = sy;
    __syncthreads();
    for (int off = 128; off > 0; off >>= 1) {
        if (t < off) { redx[t] += redx[t + off]; redy[t] += redy[t + off]; }
        __syncthreads();
    }
    const float inv_sx = 1.0f / redx[0];
    const float inv_sy = 1.0f / redy[0];
    #pragma unroll
    for (int k = 0; k < 8; ++k) {
        int p = t + 256 * k;
        float a0 = xm0[k], a1 = xm1[k], b0 = ym0[k], b1 = ym1[k];
        float qx = fmaf(a0, a0, a1 * a1);
        float qy = fmaf(b0, b0, b1 * b1);
        float mu = a1 * a1 * inv_sx;
        float nu = b1 * b1 * inv_sy;
        // B = log2(marginal + 1e-8) + s*|pt|^2 (cancels dropped row constant)
        float Bmu = __builtin_amdgcn_logf(mu + 1e-8f) + SCALE * qx;
        float Bnu = __builtin_amdgcn_logf(nu + 1e-8f) + SCALE * qy;
        size_t idx = (size_t)n * P + p;
        rowX[idx] = make_float4(a0, a1, Bmu, 0.f);
        rowY[idx] = make_float4(b0, b1, Bnu, 0.f);
        jpX[idx] = make_float2(2.f * SCALE * a0, 2.f * SCALE * a1);
        jpY[idx] = make_float2(2.f * SCALE * b0, 2.f * SCALE * b1);
        u[idx] = 0.f;
        v[idx] = 0.f;
    }
    if (n == 0) {
        partial[t] = 0.f; partial[t + 256] = 0.f;
        flags[t] = 0u; flags[t + 256] = 0u;
    }
}

// j <-> (lane, k) mapping: j = lane*32 + k  (lane-contiguous, dwordx4 loads).
__device__ __forceinline__ void load_Y(const vf4* __restrict__ p,
                                       float (&Y0)[32], float (&Y1)[32]) {
    #pragma unroll
    for (int m = 0; m < 16; ++m) {
        vf4 q = p[m];
        Y0[2 * m] = q[0];     Y1[2 * m] = q[1];
        Y0[2 * m + 1] = q[2]; Y1[2 * m + 1] = q[3];
    }
}

// out_i = B_i - log2( sum_j 2^( V_j + Y0_j*x0_i + Y1_j*x1_i ) )
__device__ __forceinline__ float rowsum(const float (&Y0)[32], const float (&Y1)[32],
                                        const float (&V)[32], float x0, float x1) {
    float a0 = 0.f, a1 = 0.f, a2 = 0.f, a3 = 0.f;
    #pragma unroll
    for (int k = 0; k < 32; k += 4) {
        a0 += __builtin_amdgcn_exp2f(fmaf(Y1[k + 0], x1, fmaf(Y0[k + 0], x0, V[k + 0])));
        a1 += __builtin_amdgcn_exp2f(fmaf(Y1[k + 1], x1, fmaf(Y0[k + 1], x0, V[k + 1])));
        a2 += __builtin_amdgcn_exp2f(fmaf(Y1[k + 2], x1, fmaf(Y0[k + 2], x0, V[k + 2])));
        a3 += __builtin_amdgcn_exp2f(fmaf(Y1[k + 3], x1, fmaf(Y0[k + 3], x0, V[k + 3])));
    }
    return (a0 + a1) + (a2 + a3);
}

__device__ __forceinline__ void half_phase(const float (&Y0)[32], const float (&Y1)[32],
                                           const float* __restrict__ din,
                                           const float4* __restrict__ rdat,
                                           float* __restrict__ dout,
                                           const int lane, const int rowbase) {
    // V_j = dual_j - Q_j, Q recomputed from Y0,Y1: Q = (Y0^2 + Y1^2)/(4S)
    float V[32];
    const vf4* dp = (const vf4*)(din + (size_t)lane * 32);
    #pragma unroll
    for (int k8 = 0; k8 < 8; ++k8) {
        vf4 d = dp[k8];
        #pragma unroll
        for (int e = 0; e < 4; ++e) {
            int k = k8 * 4 + e;
            float q = fmaf(Y0[k], Y0[k], Y1[k] * Y1[k]);
            V[k] = fmaf(q, -INV4S, d[e]);
        }
    }
    float acc[8], Bs[8];
    #pragma unroll
    for (int r = 0; r < 8; ++r) {
        float4 rv = rdat[rowbase + r];     // wave-uniform
        Bs[r] = rv.z;
        acc[r] = rowsum(Y0, Y1, V, rv.x, rv.y);
    }
    // 8 independent butterflies (pipelined, not 8 serial dependent chains)
    #pragma unroll
    for (int r = 0; r < 8; ++r) {
        float a = acc[r];
        #pragma unroll
        for (int m = 1; m < 64; m <<= 1) a += __shfl_xor(a, m, 64);
        acc[r] = a;
    }
    if (lane == 0) {
        #pragma unroll
        for (int r = 0; r < 8; ++r)
            dout[rowbase + r] = Bs[r] - __builtin_amdgcn_logf(acc[r]);
    }
}

// Arrival: own-slot release store. Detection: wave0, per-lane relaxed load of
// all 64 flags + __all, then agent acquire fence. Deadman: ~16k polls at
// ~0.2us => ~3ms/barrier worst case; a tripped deadman produces wrong output
// (visible verification failure), never a watchdog hang.
__device__ __forceinline__ void flag_barrier(unsigned* __restrict__ fl,
                                             int blkin, int wave, int lane,
                                             unsigned ep) {
    __syncthreads();                       // drains each wave's vmcnt (stores done)
    if (threadIdx.x == 0)
        __hip_atomic_store(fl + blkin, ep, __ATOMIC_RELEASE, __HIP_MEMORY_SCOPE_AGENT);
    if (wave == 0) {
        int guard = 0;
        unsigned f = __hip_atomic_load(fl + lane, __ATOMIC_RELAXED, __HIP_MEMORY_SCOPE_AGENT);
        while (!__all(f >= ep)) {
            __builtin_amdgcn_s_sleep(8);
            f = __hip_atomic_load(fl + lane, __ATOMIC_RELAXED, __HIP_MEMORY_SCOPE_AGENT);
            if (++guard > (1 << 14)) break;
        }
        __builtin_amdgcn_fence(__ATOMIC_ACQUIRE, "agent");
    }
    __syncthreads();
}

// 512 blocks x 256 threads, 2 blocks/CU -> all co-resident (proven by v2/v3
// passing with spin barriers). batch = blk&7; each block owns 32 rows of its
// batch for BOTH half-updates.
__global__ __launch_bounds__(256, 2) void sinkhorn_iter_kernel(
        const float2* __restrict__ jpY, const float2* __restrict__ jpX,
        const float4* __restrict__ rowX, const float4* __restrict__ rowY,
        float* __restrict__ u, float* __restrict__ v, unsigned* __restrict__ flags) {
    const int blk = blockIdx.x;
    const int batch = blk & 7;
    const int blkin = blk >> 3;               // 0..63
    const int lane = threadIdx.x & 63;
    const int wave = threadIdx.x >> 6;        // 0..3
    const int rowbase = blkin * 32 + wave * 8;

    const vf4* py = (const vf4*)((const float2*)(jpY + (size_t)batch * P) + (size_t)lane * 32);
    const vf4* px = (const vf4*)((const float2*)(jpX + (size_t)batch * P) + (size_t)lane * 32);
    const float4* rX = rowX + (size_t)batch * P;
    const float4* rY = rowY + (size_t)batch * P;
    float* ub = u + (size_t)batch * P;
    float* vb = v + (size_t)batch * P;
    unsigned* fl = flags + (size_t)batch * 64;   // 256B region, own slot fl[blkin]

    float A0[32], A1[32], B0[32], B1[32];
    load_Y(py, A0, A1);                        // phase 0 factors (y side)

    unsigned ep = 0;
    for (int it = 0; it < 50; ++it) {
        // ---- u-update: reduce over j (y side), reads v, writes u ----
        half_phase(A0, A1, vb, rX, ub, lane, rowbase);
        ++ep;
        __syncthreads();
        if (threadIdx.x == 0)
            __hip_atomic_store(fl + blkin, ep, __ATOMIC_RELEASE, __HIP_MEMORY_SCOPE_AGENT);
        load_Y(px, B0, B1);                    // prefetch x-side under barrier wait
        if (wave == 0) {
            int guard = 0;
            unsigned f = __hip_atomic_load(fl + lane, __ATOMIC_RELAXED, __HIP_MEMORY_SCOPE_AGENT);
            while (!__all(f >= ep)) {
                __builtin_amdgcn_s_sleep(8);
                f = __hip_atomic_load(fl + lane, __ATOMIC_RELAXED, __HIP_MEMORY_SCOPE_AGENT);
                if (++guard > (1 << 14)) break;  // deadman: fail visibly, fast
            }
            __builtin_amdgcn_fence(__ATOMIC_ACQUIRE, "agent");
        }
        __syncthreads();

        // ---- v-update: reduce over i (x side), reads u, writes v ----
        half_phase(B0, B1, ub, rY, vb, lane, rowbase);
        if (it < 49) {
            ++ep;
            __syncthreads();
            if (threadIdx.x == 0)
                __hip_atomic_store(fl + blkin, ep, __ATOMIC_RELEASE, __HIP_MEMORY_SCOPE_AGENT);
            load_Y(py, A0, A1);                // prefetch y-side under barrier wait
            if (wave == 0) {
                int guard = 0;
                unsigned f = __hip_atomic_load(fl + lane, __ATOMIC_RELAXED, __HIP_MEMORY_SCOPE_AGENT);
                while (!__all(f >= ep)) {
                    __builtin_amdgcn_s_sleep(8);
                    f = __hip_atomic_load(fl + lane, __ATOMIC_RELAXED, __HIP_MEMORY_SCOPE_AGENT);
                    if (++guard > (1 << 14)) break;
                }
                __builtin_amdgcn_fence(__ATOMIC_ACQUIRE, "agent");
            }
            __syncthreads();
        }
    }
}

// Final: pi = 2^(u~_i + v~_j - s*C_ij), C, and cost partials.
__global__ void final_kernel(const float4* __restrict__ rowX, const float4* __restrict__ rowY,
                             const float* __restrict__ u, const float* __restrict__ v,
                             float* __restrict__ out, float* __restrict__ partial) {
    const int blk = blockIdx.x;
    const int batch = blk & 7;
    const int i = blk >> 3;
    const int t = threadIdx.x;

    const float4 rx = rowX[(size_t)batch * P + i];
    const float ui = u[(size_t)batch * P + i];
    const float x0 = rx.x, x1 = rx.y;

    float* pi_out = out + 8 + (size_t)batch * P * P + (size_t)i * P;
    float* C_out = pi_out + (size_t)NB * P * P;
    const float4* ry = rowY + (size_t)batch * P;
    const float* vv = v + (size_t)batch * P;

    float costacc = 0.f;
    #pragma unroll
    for (int c = 0; c < 2; ++c) {
        const int j0 = c * 1024 + t * 4;
        vf4 vj = *(const vf4*)(vv + j0);
        vf4 Cv, Pv;
        #pragma unroll
        for (int e = 0; e < 4; ++e) {
            float4 q = ry[j0 + e];
            float dx = x0 - q.x;
            float dy = x1 - q.y;
            float Cj = fmaf(dy, dy, dx * dx);
            float pj = __builtin_amdgcn_exp2f(fmaf(Cj, -SCALE, ui + vj[e]));
            Cv[e] = Cj;
            Pv[e] = pj;
            costacc = fmaf(pj, Cj, costacc);
        }
        __builtin_nontemporal_store(Pv, (vf4*)(pi_out + j0));
        __builtin_nontemporal_store(Cv, (vf4*)(C_out + j0));
    }

    #pragma unroll
    for (int m = 1; m < 64; m <<= 1) costacc += __shfl_xor(costacc, m, 64);
    __shared__ float sred[4];
    const int wave = t >> 6, lane = t & 63;
    if (lane == 0) sred[wave] = costacc;
    __syncthreads();
    if (t == 0) {
        float s = sred[0] + sred[1] + sred[2] + sred[3];
        atomicAdd(&partial[batch * 64 + (i & 63)], s);
    }
}

__global__ void costreduce_kernel(const float* __restrict__ partial, float* __restrict__ out) {
    const int t = threadIdx.x; // 512 threads: wave w reduces batch w's 64 slots
    float val = partial[t];
    #pragma unroll
    for (int m = 1; m < 64; m <<= 1) val += __shfl_xor(val, m, 64);
    if ((t & 63) == 0) out[t >> 6] = val;
}

extern "C" void kernel_launch(void* const* d_in, const int* in_sizes, int n_in,
                              void* d_out, int out_size, void* d_ws, size_t ws_size,
                              hipStream_t stream) {
    const float* x = (const float*)d_in[0];
    const float* y = (const float*)d_in[1];
    float* out = (float*)d_out;
    float* ws = (float*)d_ws;

    float2* jpY = (float2*)ws;
    float2* jpX = (float2*)(ws + 32768);
    float4* rowX = (float4*)(ws + 65536);
    float4* rowY = (float4*)(ws + 131072);
    float* u = ws + 196608;
    float* v = ws + 196608 + 16384;
    float* partial = ws + 196608 + 32768;
    unsigned* flags = (unsigned*)(ws + 196608 + 32768 + 512);

    setup_kernel<<<8, 256, 0, stream>>>(x, y, jpY, jpX, rowX, rowY, u, v, partial, flags);
    sinkhorn_iter_kernel<<<512, 256, 0, stream>>>(jpY, jpX, rowX, rowY, u, v, flags);
    final_kernel<<<16384, 256, 0, stream>>>(rowX, rowY, u, v, out, partial);
    costreduce_kernel<<<1, 512, 0, stream>>>(partial, out);
}

// Round 5
// 1673.788 us; speedup vs baseline: 1.4840x; 1.4840x over previous
//
#include <hip/hip_runtime.h>

// Sinkhorn distance, 8 batches x 2048 points x 2 dims, 50 iters, eps=0.1.
// v6: persistent kernel with FENCELESS cross-block sync. v2-v5 showed a
// design-independent ~15-18us/crossing cost == the agent-scope release/
// acquire fences (buffer_wbl2 + L2 invalidate, which also evicted all
// read-only data every phase). v6 removes ALL fences: the only shared data
// (u/v duals + flags) moves through the IC explicitly via sc0 sc1 (bypass
// L1/L2, service at the agent-coherent point) loads/stores with manual
// vmcnt ordering. Read-only j-factors/rowdat stay warm in L1/L2 forever.

#define P 2048
#define NB 8
constexpr float SCALE = 14.426950408889634f; // log2(e) / eps, eps = 0.1
constexpr float INV4S = 1.0f / (4.0f * SCALE);

typedef float vf4 __attribute__((ext_vector_type(4)));

// ws layout (floats):
// 0       jpY   float2[8*2048]   (32768 f)
// 32768   jpX   float2[8*2048]   (32768 f)
// 65536   rowX  float4[8*2048]   (65536 f)
// 131072  rowY  float4[8*2048]   (65536 f)
// 196608  u[16384]
// 212992  v[16384]
// 229376  partial[512]
// 229888  flags: unsigned[512]  — flags[b*64 + i], 256B per batch

__global__ void setup_kernel(const float* __restrict__ x, const float* __restrict__ yy,
                             float2* __restrict__ jpY, float2* __restrict__ jpX,
                             float4* __restrict__ rowX, float4* __restrict__ rowY,
                             float* __restrict__ u, float* __restrict__ v,
                             float* __restrict__ partial, unsigned* __restrict__ flags) {
    const int n = blockIdx.x;
    const int t = threadIdx.x;
    __shared__ float redx[256], redy[256];
    float xm0[8], xm1[8], ym0[8], ym1[8];
    float sx = 0.f, sy = 0.f;
    #pragma unroll
    for (int k = 0; k < 8; ++k) {
        int p = t + 256 * k;
        size_t base = ((size_t)n * P + p) * 2;
        float a0 = x[base + 0];
        float a1 = x[base + 1];
        float b0 = yy[base + 0];
        float b1 = yy[base + 1];
        // mask = (x != -1); applied to BOTH x and y (per reference)
        float m0 = (a0 != -1.0f) ? 1.0f : 0.0f;
        float m1 = (a1 != -1.0f) ? 1.0f : 0.0f;
        a0 *= m0; a1 *= m1; b0 *= m0; b1 *= m1;
        xm0[k] = a0; xm1[k] = a1; ym0[k] = b0; ym1[k] = b1;
        sx = fmaf(a1, a1, sx);
        sy = fmaf(b1, b1, sy);
    }
    redx[t] = sx; redy[t] = sy;
    __syncthreads();
    for (int off = 128; off > 0; off >>= 1) {
        if (t < off) { redx[t] += redx[t + off]; redy[t] += redy[t + off]; }
        __syncthreads();
    }
    const float inv_sx = 1.0f / redx[0];
    const float inv_sy = 1.0f / redy[0];
    #pragma unroll
    for (int k = 0; k < 8; ++k) {
        int p = t + 256 * k;
        float a0 = xm0[k], a1 = xm1[k], b0 = ym0[k], b1 = ym1[k];
        float qx = fmaf(a0, a0, a1 * a1);
        float qy = fmaf(b0, b0, b1 * b1);
        float mu = a1 * a1 * inv_sx;
        float nu = b1 * b1 * inv_sy;
        // B = log2(marginal + 1e-8) + s*|pt|^2 (cancels dropped row constant)
        float Bmu = __builtin_amdgcn_logf(mu + 1e-8f) + SCALE * qx;
        float Bnu = __builtin_amdgcn_logf(nu + 1e-8f) + SCALE * qy;
        size_t idx = (size_t)n * P + p;
        rowX[idx] = make_float4(a0, a1, Bmu, 0.f);
        rowY[idx] = make_float4(b0, b1, Bnu, 0.f);
        jpX[idx] = make_float2(2.f * SCALE * a0, 2.f * SCALE * a1);
        jpY[idx] = make_float2(2.f * SCALE * b0, 2.f * SCALE * b1);
        u[idx] = 0.f;
        v[idx] = 0.f;
    }
    if (n == 0) {
        partial[t] = 0.f; partial[t + 256] = 0.f;
        flags[t] = 0u; flags[t + 256] = 0u;
    }
}

// j <-> (lane, k) mapping: j = lane*32 + k  (lane-contiguous, dwordx4 loads).
__device__ __forceinline__ void load_Y(const vf4* __restrict__ p,
                                       float (&Y0)[32], float (&Y1)[32]) {
    #pragma unroll
    for (int m = 0; m < 16; ++m) {
        vf4 q = p[m];
        Y0[2 * m] = q[0];     Y1[2 * m] = q[1];
        Y0[2 * m + 1] = q[2]; Y1[2 * m + 1] = q[3];
    }
}

// out_i = B_i - log2( sum_j 2^( V_j + Y0_j*x0_i + Y1_j*x1_i ) )
__device__ __forceinline__ float rowsum(const float (&Y0)[32], const float (&Y1)[32],
                                        const float (&V)[32], float x0, float x1) {
    float a0 = 0.f, a1 = 0.f, a2 = 0.f, a3 = 0.f;
    #pragma unroll
    for (int k = 0; k < 32; k += 4) {
        a0 += __builtin_amdgcn_exp2f(fmaf(Y1[k + 0], x1, fmaf(Y0[k + 0], x0, V[k + 0])));
        a1 += __builtin_amdgcn_exp2f(fmaf(Y1[k + 1], x1, fmaf(Y0[k + 1], x0, V[k + 1])));
        a2 += __builtin_amdgcn_exp2f(fmaf(Y1[k + 2], x1, fmaf(Y0[k + 2], x0, V[k + 2])));
        a3 += __builtin_amdgcn_exp2f(fmaf(Y1[k + 3], x1, fmaf(Y0[k + 3], x0, V[k + 3])));
    }
    return (a0 + a1) + (a2 + a3);
}

// Dual read: 8x dwordx4 from the coherent point (sc0 sc1 bypasses the stale
// L1/L2), ONE latency for all 8, no fence needed.
__device__ __forceinline__ void load_duals_coherent(const float* __restrict__ din,
                                                    int lane, vf4 (&dv)[8]) {
    const float* dbase = din + (size_t)lane * 32;
    asm volatile(
        "global_load_dwordx4 %0, %8, off sc0 sc1\n\t"
        "global_load_dwordx4 %1, %8, off offset:16 sc0 sc1\n\t"
        "global_load_dwordx4 %2, %8, off offset:32 sc0 sc1\n\t"
        "global_load_dwordx4 %3, %8, off offset:48 sc0 sc1\n\t"
        "global_load_dwordx4 %4, %8, off offset:64 sc0 sc1\n\t"
        "global_load_dwordx4 %5, %8, off offset:80 sc0 sc1\n\t"
        "global_load_dwordx4 %6, %8, off offset:96 sc0 sc1\n\t"
        "global_load_dwordx4 %7, %8, off offset:112 sc0 sc1\n\t"
        "s_waitcnt vmcnt(0)"
        : "=&v"(dv[0]), "=&v"(dv[1]), "=&v"(dv[2]), "=&v"(dv[3]),
          "=&v"(dv[4]), "=&v"(dv[5]), "=&v"(dv[6]), "=&v"(dv[7])
        : "v"(dbase)
        : "memory");
}

__device__ __forceinline__ void half_phase(const float (&Y0)[32], const float (&Y1)[32],
                                           const float* __restrict__ din,
                                           const float4* __restrict__ rdat,
                                           float* __restrict__ dout,
                                           const int lane, const int rowbase) {
    // V_j = dual_j - Q_j, Q recomputed from Y0,Y1: Q = (Y0^2 + Y1^2)/(4S)
    vf4 dv[8];
    load_duals_coherent(din, lane, dv);
    float V[32];
    #pragma unroll
    for (int k8 = 0; k8 < 8; ++k8) {
        #pragma unroll
        for (int e = 0; e < 4; ++e) {
            int k = k8 * 4 + e;
            float q = fmaf(Y0[k], Y0[k], Y1[k] * Y1[k]);
            V[k] = fmaf(q, -INV4S, dv[k8][e]);
        }
    }
    float acc[8], Bs[8];
    #pragma unroll
    for (int r = 0; r < 8; ++r) {
        float4 rv = rdat[rowbase + r];     // wave-uniform, cached (read-only)
        Bs[r] = rv.z;
        acc[r] = rowsum(Y0, Y1, V, rv.x, rv.y);
    }
    // 8 independent butterflies (pipelined, not 8 serial dependent chains)
    #pragma unroll
    for (int r = 0; r < 8; ++r) {
        float a = acc[r];
        #pragma unroll
        for (int m = 1; m < 64; m <<= 1) a += __shfl_xor(a, m, 64);
        acc[r] = a;
    }
    if (lane == 0) {
        vf4 o0, o1;
        #pragma unroll
        for (int r = 0; r < 4; ++r) {
            o0[r] = Bs[r] - __builtin_amdgcn_logf(acc[r]);
            o1[r] = Bs[r + 4] - __builtin_amdgcn_logf(acc[r + 4]);
        }
        // Store straight to the coherent point; vmcnt drain = this wave's
        // release point (no wbl2: nothing dirty in L2 to publish).
        float* dptr = dout + rowbase;
        asm volatile(
            "global_store_dwordx4 %0, %1, off sc0 sc1\n\t"
            "global_store_dwordx4 %0, %2, off offset:16 sc0 sc1\n\t"
            "s_waitcnt vmcnt(0)"
            :: "v"(dptr), "v"(o0), "v"(o1)
            : "memory");
    }
}

// Arrival: own-slot coherent store (after syncthreads: all waves' coherent
// dual stores already drained). Detection: wave0 polls all 64 flags with one
// per-lane coherent load + __all. No fences anywhere. Deadman ~3ms/barrier:
// fails verification visibly, never trips the watchdog.
__device__ __forceinline__ void flag_barrier(unsigned* __restrict__ fl,
                                             int blkin, int wave, int lane,
                                             unsigned ep) {
    __syncthreads();
    if (threadIdx.x == 0) {
        asm volatile("global_store_dword %0, %1, off sc0 sc1"
                     :: "v"(fl + blkin), "v"(ep) : "memory");
    }
    if (wave == 0) {
        const unsigned* fp = fl + lane;
        int guard = 0;
        unsigned f;
        for (;;) {
            asm volatile("global_load_dword %0, %1, off sc0 sc1\n\t"
                         "s_waitcnt vmcnt(0)"
                         : "=&v"(f) : "v"(fp) : "memory");
            if (__all(f >= ep)) break;
            __builtin_amdgcn_s_sleep(8);
            if (++guard > (1 << 14)) break;    // deadman: fail visibly, fast
        }
    }
    __syncthreads();
}

// 512 blocks x 256 threads, 2 blocks/CU -> all co-resident (proven v2-v5).
// batch = blk&7; each block owns 32 rows of its batch for BOTH half-updates.
__global__ __launch_bounds__(256, 2) void sinkhorn_iter_kernel(
        const float2* __restrict__ jpY, const float2* __restrict__ jpX,
        const float4* __restrict__ rowX, const float4* __restrict__ rowY,
        float* __restrict__ u, float* __restrict__ v, unsigned* __restrict__ flags) {
    const int blk = blockIdx.x;
    const int batch = blk & 7;
    const int blkin = blk >> 3;               // 0..63
    const int lane = threadIdx.x & 63;
    const int wave = threadIdx.x >> 6;        // 0..3
    const int rowbase = blkin * 32 + wave * 8;

    const vf4* py = (const vf4*)((const float2*)(jpY + (size_t)batch * P) + (size_t)lane * 32);
    const vf4* px = (const vf4*)((const float2*)(jpX + (size_t)batch * P) + (size_t)lane * 32);
    const float4* rX = rowX + (size_t)batch * P;
    const float4* rY = rowY + (size_t)batch * P;
    float* ub = u + (size_t)batch * P;
    float* vb = v + (size_t)batch * P;
    unsigned* fl = flags + (size_t)batch * 64;   // 256B region, own slot fl[blkin]

    float Y0[32], Y1[32];                     // one buffer, reloaded per phase
    unsigned ep = 0;                          // (plain cached loads, L2-warm —
                                              //  no fences ever evict them)
    for (int it = 0; it < 50; ++it) {
        // ---- u-update: reduce over j (y side), reads v, writes u ----
        load_Y(py, Y0, Y1);
        half_phase(Y0, Y1, vb, rX, ub, lane, rowbase);
        ++ep;
        flag_barrier(fl, blkin, wave, lane, ep);

        // ---- v-update: reduce over i (x side), reads u, writes v ----
        load_Y(px, Y0, Y1);
        half_phase(Y0, Y1, ub, rY, vb, lane, rowbase);
        if (it < 49) {
            ++ep;
            flag_barrier(fl, blkin, wave, lane, ep);
        }
    }
}

// Final: pi = 2^(u~_i + v~_j - s*C_ij), C, and cost partials.
// (kernel boundary makes iter's coherent stores visible to plain loads)
__global__ void final_kernel(const float4* __restrict__ rowX, const float4* __restrict__ rowY,
                             const float* __restrict__ u, const float* __restrict__ v,
                             float* __restrict__ out, float* __restrict__ partial) {
    const int blk = blockIdx.x;
    const int batch = blk & 7;
    const int i = blk >> 3;
    const int t = threadIdx.x;

    const float4 rx = rowX[(size_t)batch * P + i];
    const float ui = u[(size_t)batch * P + i];
    const float x0 = rx.x, x1 = rx.y;

    float* pi_out = out + 8 + (size_t)batch * P * P + (size_t)i * P;
    float* C_out = pi_out + (size_t)NB * P * P;
    const float4* ry = rowY + (size_t)batch * P;
    const float* vv = v + (size_t)batch * P;

    float costacc = 0.f;
    #pragma unroll
    for (int c = 0; c < 2; ++c) {
        const int j0 = c * 1024 + t * 4;
        vf4 vj = *(const vf4*)(vv + j0);
        vf4 Cv, Pv;
        #pragma unroll
        for (int e = 0; e < 4; ++e) {
            float4 q = ry[j0 + e];
            float dx = x0 - q.x;
            float dy = x1 - q.y;
            float Cj = fmaf(dy, dy, dx * dx);
            float pj = __builtin_amdgcn_exp2f(fmaf(Cj, -SCALE, ui + vj[e]));
            Cv[e] = Cj;
            Pv[e] = pj;
            costacc = fmaf(pj, Cj, costacc);
        }
        __builtin_nontemporal_store(Pv, (vf4*)(pi_out + j0));
        __builtin_nontemporal_store(Cv, (vf4*)(C_out + j0));
    }

    #pragma unroll
    for (int m = 1; m < 64; m <<= 1) costacc += __shfl_xor(costacc, m, 64);
    __shared__ float sred[4];
    const int wave = t >> 6, lane = t & 63;
    if (lane == 0) sred[wave] = costacc;
    __syncthreads();
    if (t == 0) {
        float s = sred[0] + sred[1] + sred[2] + sred[3];
        atomicAdd(&partial[batch * 64 + (i & 63)], s);
    }
}

__global__ void costreduce_kernel(const float* __restrict__ partial, float* __restrict__ out) {
    const int t = threadIdx.x; // 512 threads: wave w reduces batch w's 64 slots
    float val = partial[t];
    #pragma unroll
    for (int m = 1; m < 64; m <<= 1) val += __shfl_xor(val, m, 64);
    if ((t & 63) == 0) out[t >> 6] = val;
}

extern "C" void kernel_launch(void* const* d_in, const int* in_sizes, int n_in,
                              void* d_out, int out_size, void* d_ws, size_t ws_size,
                              hipStream_t stream) {
    const float* x = (const float*)d_in[0];
    const float* y = (const float*)d_in[1];
    float* out = (float*)d_out;
    float* ws = (float*)d_ws;

    float2* jpY = (float2*)ws;
    float2* jpX = (float2*)(ws + 32768);
    float4* rowX = (float4*)(ws + 65536);
    float4* rowY = (float4*)(ws + 131072);
    float* u = ws + 196608;
    float* v = ws + 196608 + 16384;
    float* partial = ws + 196608 + 32768;
    unsigned* flags = (unsigned*)(ws + 196608 + 32768 + 512);

    setup_kernel<<<8, 256, 0, stream>>>(x, y, jpY, jpX, rowX, rowY, u, v, partial, flags);
    sinkhorn_iter_kernel<<<512, 256, 0, stream>>>(jpY, jpX, rowX, rowY, u, v, flags);
    final_kernel<<<16384, 256, 0, stream>>>(rowX, rowY, u, v, out, partial);
    costreduce_kernel<<<1, 512, 0, stream>>>(partial, out);
}